// Round 1
// baseline (158.797 us; speedup 1.0000x reference)
//
#include <hip/hip_runtime.h>
#include <math.h>

// Problem constants (fixed by reference setup_inputs)
constexpr int N = 8;
constexpr int H = 256;
constexpr int W = 256;
constexpr int NPIX = N * H * W;          // 524288
constexpr float FEPS = 1e-6f;
constexpr float FINF = 1e10f;

// ws layout (floats):
//   [0, 2*NPIX)              : d1 as float2 per pixel (dfg, dbg), [N][H][W]
//   [2*NPIX, 2*NPIX+5*2048)  : 5 partial arrays of nblocks floats each
//                              (q=0: sum p*t, 1: sum p, 2: sum t, 3: sum phi*p, 4: sum focal)

// -------- Kernel 1: per-row 1D squared-distance transform (fg and bg) --------
__global__ __launch_bounds__(256) void row_pass_kernel(
    const float* __restrict__ tgt, float2* __restrict__ d1)
{
    const int b  = blockIdx.x;          // n*H + qy
    const int px = threadIdx.x;
    __shared__ int fg[W];
    const float tv = tgt[b * W + px];
    fg[px] = (tv > 0.5f) ? 1 : 0;
    __syncthreads();

    float dfg = FINF, dbg = FINF;
    #pragma unroll 4
    for (int qx = 0; qx < W; ++qx) {
        const float dx  = (float)(px - qx);
        const float dx2 = dx * dx;
        // fg[qx] is uniform across the wave -> no divergence
        if (fg[qx]) dfg = fminf(dfg, dx2);
        else        dbg = fminf(dbg, dx2);
    }
    d1[b * W + px] = make_float2(dfg, dbg);
}

// -------- Kernel 2: column pass + sigmoid/dice/focal/boundary + block reduce --------
__global__ __launch_bounds__(256) void main_pass_kernel(
    const float* __restrict__ pred, const float* __restrict__ tgt,
    const float2* __restrict__ d1, float* __restrict__ parts, int nblocks)
{
    const int b   = blockIdx.x;         // n*H + py
    const int n   = b >> 8;
    const int py  = b & 255;
    const int px  = threadIdx.x;
    const int idx = b * W + px;

    const float x = pred[idx];
    const float t = tgt[idx];
    const float p = 1.0f / (1.0f + expf(-x));
    const bool fgpix = t > 0.5f;

    // exact EDT column pass: min over qy of (py-qy)^2 + d1[n][qy][px]
    const float2* col = d1 + (size_t)n * (H * W) + px;
    float dfg = FINF, dbg = FINF;
    #pragma unroll 8
    for (int qy = 0; qy < H; ++qy) {
        const float dy  = (float)(py - qy);
        const float dy2 = dy * dy;
        const float2 v  = col[(size_t)qy * W];
        dfg = fminf(dfg, dy2 + v.x);
        dbg = fminf(dbg, dy2 + v.y);
    }
    const float MAXD2 = (float)((H - 1) * (H - 1) + (W - 1) * (W - 1));
    if (dfg > 0.5f * FINF) dfg = MAXD2;   // empty-foreground fallback
    if (dbg > 0.5f * FINF) dbg = MAXD2;
    const float phi = fgpix ? -sqrtf(dbg) : sqrtf(dfg);

    // focal (uses the raw float target, not the binarized mask)
    const float pc = fminf(fmaxf(p, FEPS), 1.0f - FEPS);
    const float pt = pc * t + (1.0f - pc) * (1.0f - t);
    const float at = 0.25f * t + 0.75f * (1.0f - t);
    const float om = 1.0f - pt;
    const float focal = -at * om * om * logf(pt);

    float v5[5] = { p * t, p, t, phi * p, focal };

    // block reduction: wave-64 shuffle then cross-wave via LDS
    __shared__ float smem[4 * 5];
    const int lane = threadIdx.x & 63;
    const int wid  = threadIdx.x >> 6;
    #pragma unroll
    for (int q = 0; q < 5; ++q) {
        float v = v5[q];
        #pragma unroll
        for (int off = 32; off > 0; off >>= 1) v += __shfl_down(v, off, 64);
        v5[q] = v;
    }
    if (lane == 0) {
        #pragma unroll
        for (int q = 0; q < 5; ++q) smem[wid * 5 + q] = v5[q];
    }
    __syncthreads();
    if (threadIdx.x == 0) {
        #pragma unroll
        for (int q = 0; q < 5; ++q) {
            const float s = smem[q] + smem[5 + q] + smem[10 + q] + smem[15 + q];
            parts[q * nblocks + b] = s;
        }
    }
}

// -------- Kernel 3: final reduction to the 4 scalars --------
__global__ __launch_bounds__(256) void finalize_kernel(
    const float* __restrict__ parts, float* __restrict__ out, int nblocks)
{
    const int tid  = threadIdx.x;       // 256 threads
    const int lane = tid & 63;
    const int wid  = tid >> 6;
    __shared__ float smem[4 * 3];
    __shared__ float smem2[4 * 2];

    // dice: per-image sums over the image's 256 blocks
    float dice_acc = 0.0f;              // meaningful on thread 0 only
    for (int n = 0; n < N; ++n) {
        const int i = n * 256 + tid;
        float a = parts[0 * nblocks + i];
        float s = parts[1 * nblocks + i];
        float c = parts[2 * nblocks + i];
        #pragma unroll
        for (int off = 32; off > 0; off >>= 1) {
            a += __shfl_down(a, off, 64);
            s += __shfl_down(s, off, 64);
            c += __shfl_down(c, off, 64);
        }
        if (lane == 0) { smem[wid*3+0] = a; smem[wid*3+1] = s; smem[wid*3+2] = c; }
        __syncthreads();
        if (tid == 0) {
            const float A = smem[0] + smem[3] + smem[6] + smem[9];
            const float S = smem[1] + smem[4] + smem[7] + smem[10];
            const float C = smem[2] + smem[5] + smem[8] + smem[11];
            dice_acc += (2.0f * A + FEPS) / (S + C + FEPS);
        }
        __syncthreads();
    }

    // boundary + focal: global sums over all nblocks partials
    float bp = 0.0f, fc = 0.0f;
    for (int k = tid; k < nblocks; k += 256) {
        bp += parts[3 * nblocks + k];
        fc += parts[4 * nblocks + k];
    }
    #pragma unroll
    for (int off = 32; off > 0; off >>= 1) {
        bp += __shfl_down(bp, off, 64);
        fc += __shfl_down(fc, off, 64);
    }
    if (lane == 0) { smem2[wid*2+0] = bp; smem2[wid*2+1] = fc; }
    __syncthreads();
    if (tid == 0) {
        const float B = smem2[0] + smem2[2] + smem2[4] + smem2[6];
        const float F = smem2[1] + smem2[3] + smem2[5] + smem2[7];
        const float dice_val     = 1.0f - dice_acc / (float)N;
        const float boundary_val = B / (float)NPIX;
        const float focal_val    = F / (float)NPIX;
        out[0] = dice_val + boundary_val + focal_val;   // loss
        out[1] = dice_val;
        out[2] = boundary_val;
        out[3] = focal_val;
    }
}

extern "C" void kernel_launch(void* const* d_in, const int* in_sizes, int n_in,
                              void* d_out, int out_size, void* d_ws, size_t ws_size,
                              hipStream_t stream)
{
    const float* pred = (const float*)d_in[0];
    const float* tgt  = (const float*)d_in[1];
    float* out = (float*)d_out;

    float2* d1   = (float2*)d_ws;                    // NPIX float2 = 4 MB
    float* parts = (float*)d_ws + 2 * (size_t)NPIX;  // 5 * 2048 floats

    const int nblocks = N * H;                       // 2048

    row_pass_kernel<<<nblocks, 256, 0, stream>>>(tgt, d1);
    main_pass_kernel<<<nblocks, 256, 0, stream>>>(pred, tgt, d1, parts, nblocks);
    finalize_kernel<<<1, 256, 0, stream>>>(parts, out, nblocks);
}

// Round 2
// 95.296 us; speedup vs baseline: 1.6664x; 1.6664x over previous
//
#include <hip/hip_runtime.h>
#include <math.h>
#include <limits.h>

// Problem constants (fixed by reference setup_inputs)
constexpr int N = 8;
constexpr int H = 256;
constexpr int W = 256;
constexpr int NPIX = N * H * W;          // 524288
constexpr float FEPS = 1e-6f;
constexpr int   RSENT = 20000;           // row-empty sentinel: RSENT^2=4e8 >> legit max 130050
constexpr int   EMPTY_THRESH = 300000000;// > legit max, < RSENT^2
constexpr int   PY_PER_BLOCK = 4;
constexpr int   NBLK2 = N * H / PY_PER_BLOCK;  // 512 blocks for main pass

// ws layout:
//   short2 d1[N*H*W]                 : (r_fg, r_bg) per pixel = 2 MB
//   float  parts[5][NBLK2]           : partial sums per main-pass block
//          q=0: p*t, 1: p, 2: t, 3: phi*p, 4: focal

// -------- Kernel 1: exact 1D row distance via parallel min-scans --------
// r_fg[px] = min over fg qx of |px-qx|  (RSENT if row has no fg); same for bg.
__global__ __launch_bounds__(256) void row_scan_kernel(
    const float* __restrict__ tgt, short2* __restrict__ d1)
{
    const int b    = blockIdx.x;         // n*H + qy
    const int px   = threadIdx.x;
    const int lane = px & 63;
    const int wid  = px >> 6;
    const int BIG  = 1 << 20;

    const float tv = tgt[b * W + px];
    const bool  fg = tv > 0.5f;
    const int cf = fg ? 0 : BIG;         // cost for fg-distance
    const int cb = fg ? BIG : 0;         // cost for bg-distance

    __shared__ int sm[8];                // per-wave (fg,bg) partials

    // ---- prefix phase: fwd[i] = i + min_{j<=i} (cost_j - j) ----
    int a = cf - px, c = cb - px;
    #pragma unroll
    for (int off = 1; off < 64; off <<= 1) {
        const int ua = __shfl_up(a, off, 64);
        const int uc = __shfl_up(c, off, 64);
        if (lane >= off) { a = min(a, ua); c = min(c, uc); }
    }
    if (lane == 63) { sm[wid * 2] = a; sm[wid * 2 + 1] = c; }
    __syncthreads();
    #pragma unroll
    for (int w = 0; w < 3; ++w) {
        if (w < wid) { a = min(a, sm[w * 2]); c = min(c, sm[w * 2 + 1]); }
    }
    const int fwd_fg = px + a;
    const int fwd_bg = px + c;
    __syncthreads();

    // ---- suffix phase: bwd[i] = -i + min_{j>=i} (cost_j + j) ----
    int a2 = cf + px, c2 = cb + px;
    #pragma unroll
    for (int off = 1; off < 64; off <<= 1) {
        const int ua = __shfl_down(a2, off, 64);
        const int uc = __shfl_down(c2, off, 64);
        if (lane + off < 64) { a2 = min(a2, ua); c2 = min(c2, uc); }
    }
    if (lane == 0) { sm[wid * 2] = a2; sm[wid * 2 + 1] = c2; }
    __syncthreads();
    #pragma unroll
    for (int w = 1; w < 4; ++w) {
        if (w > wid) { a2 = min(a2, sm[w * 2]); c2 = min(c2, sm[w * 2 + 1]); }
    }
    const int bwd_fg = a2 - px;
    const int bwd_bg = c2 - px;

    int rf = min(fwd_fg, bwd_fg); if (rf > 255) rf = RSENT;
    int rb = min(fwd_bg, bwd_bg); if (rb > 255) rb = RSENT;
    d1[b * W + px] = make_short2((short)rf, (short)rb);
}

// -------- Kernel 2: column pass (4 py rows/block) + loss terms + block reduce --------
__global__ __launch_bounds__(256) void main_pass_kernel(
    const float* __restrict__ pred, const float* __restrict__ tgt,
    const short2* __restrict__ d1, float* __restrict__ parts)
{
    const int blk = blockIdx.x;              // 512
    const int n   = blk >> 6;                // image
    const int py0 = (blk & 63) * PY_PER_BLOCK;
    const int px  = threadIdx.x;

    const short2* __restrict__ col = d1 + (size_t)n * (H * W) + px;

    int dfg[PY_PER_BLOCK], dbg[PY_PER_BLOCK];
    #pragma unroll
    for (int j = 0; j < PY_PER_BLOCK; ++j) { dfg[j] = INT_MAX; dbg[j] = INT_MAX; }

    #pragma unroll 4
    for (int qy = 0; qy < H; ++qy) {
        const short2 r = col[qy * W];
        const int rf2 = (int)r.x * (int)r.x;
        const int rb2 = (int)r.y * (int)r.y;
        #pragma unroll
        for (int j = 0; j < PY_PER_BLOCK; ++j) {
            const int dy = py0 + j - qy;     // uniform across lanes -> SALU
            const int d2 = dy * dy;
            dfg[j] = min(dfg[j], d2 + rf2);
            dbg[j] = min(dbg[j], d2 + rb2);
        }
    }

    const float MAXD2 = (float)((H - 1) * (H - 1) + (W - 1) * (W - 1));
    float s0 = 0.f, s1 = 0.f, s2 = 0.f, s3 = 0.f, s4 = 0.f;
    #pragma unroll
    for (int j = 0; j < PY_PER_BLOCK; ++j) {
        const int idx = ((n * H + py0 + j) * W) + px;
        const float x = pred[idx];
        const float t = tgt[idx];
        const float p = 1.0f / (1.0f + expf(-x));

        float Dfg = (dfg[j] > EMPTY_THRESH) ? MAXD2 : (float)dfg[j];
        float Dbg = (dbg[j] > EMPTY_THRESH) ? MAXD2 : (float)dbg[j];
        const float phi = (t > 0.5f) ? -sqrtf(Dbg) : sqrtf(Dfg);

        const float pc = fminf(fmaxf(p, FEPS), 1.0f - FEPS);
        const float pt = pc * t + (1.0f - pc) * (1.0f - t);
        const float at = 0.25f * t + 0.75f * (1.0f - t);
        const float om = 1.0f - pt;
        const float focal = -at * om * om * logf(pt);

        s0 += p * t; s1 += p; s2 += t; s3 += phi * p; s4 += focal;
    }

    // block reduction of the 5 partials
    float v5[5] = { s0, s1, s2, s3, s4 };
    __shared__ float smem[4 * 5];
    const int lane = threadIdx.x & 63;
    const int wid  = threadIdx.x >> 6;
    #pragma unroll
    for (int q = 0; q < 5; ++q) {
        float v = v5[q];
        #pragma unroll
        for (int off = 32; off > 0; off >>= 1) v += __shfl_down(v, off, 64);
        v5[q] = v;
    }
    if (lane == 0) {
        #pragma unroll
        for (int q = 0; q < 5; ++q) smem[wid * 5 + q] = v5[q];
    }
    __syncthreads();
    if (threadIdx.x == 0) {
        #pragma unroll
        for (int q = 0; q < 5; ++q) {
            parts[q * NBLK2 + blk] = smem[q] + smem[5 + q] + smem[10 + q] + smem[15 + q];
        }
    }
}

// -------- Kernel 3: final reduction to the 4 scalars --------
__global__ __launch_bounds__(256) void finalize_kernel(
    const float* __restrict__ parts, float* __restrict__ out)
{
    const int tid  = threadIdx.x;        // 256 threads
    const int lane = tid & 63;
    const int wid  = tid >> 6;
    __shared__ float sm[8];
    __shared__ float sdice;

    // boundary + focal: global sums over all NBLK2 partials
    float bp = 0.0f, fc = 0.0f;
    for (int k = tid; k < NBLK2; k += 256) {
        bp += parts[3 * NBLK2 + k];
        fc += parts[4 * NBLK2 + k];
    }
    #pragma unroll
    for (int off = 32; off > 0; off >>= 1) {
        bp += __shfl_down(bp, off, 64);
        fc += __shfl_down(fc, off, 64);
    }
    if (lane == 0) { sm[wid * 2] = bp; sm[wid * 2 + 1] = fc; }

    // dice: wave 0 handles the 8 images (64 blocks each)
    if (wid == 0) {
        float dacc = 0.0f;
        for (int n = 0; n < N; ++n) {
            float A = parts[0 * NBLK2 + n * 64 + lane];
            float S = parts[1 * NBLK2 + n * 64 + lane];
            float C = parts[2 * NBLK2 + n * 64 + lane];
            #pragma unroll
            for (int off = 32; off > 0; off >>= 1) {
                A += __shfl_down(A, off, 64);
                S += __shfl_down(S, off, 64);
                C += __shfl_down(C, off, 64);
            }
            if (lane == 0) dacc += (2.0f * A + FEPS) / (S + C + FEPS);
        }
        if (lane == 0) sdice = dacc;
    }
    __syncthreads();
    if (tid == 0) {
        const float B = sm[0] + sm[2] + sm[4] + sm[6];
        const float F = sm[1] + sm[3] + sm[5] + sm[7];
        const float dice_val     = 1.0f - sdice / (float)N;
        const float boundary_val = B / (float)NPIX;
        const float focal_val    = F / (float)NPIX;
        out[0] = dice_val + boundary_val + focal_val;   // loss
        out[1] = dice_val;
        out[2] = boundary_val;
        out[3] = focal_val;
    }
}

extern "C" void kernel_launch(void* const* d_in, const int* in_sizes, int n_in,
                              void* d_out, int out_size, void* d_ws, size_t ws_size,
                              hipStream_t stream)
{
    const float* pred = (const float*)d_in[0];
    const float* tgt  = (const float*)d_in[1];
    float* out = (float*)d_out;

    short2* d1   = (short2*)d_ws;                          // 2 MB
    float*  parts = (float*)((char*)d_ws + (size_t)NPIX * sizeof(short2));

    row_scan_kernel<<<N * H, 256, 0, stream>>>(tgt, d1);
    main_pass_kernel<<<NBLK2, 256, 0, stream>>>(pred, tgt, d1, parts);
    finalize_kernel<<<1, 256, 0, stream>>>(parts, out);
}